// Round 8
// baseline (117.873 us; speedup 1.0000x reference)
//
#include <hip/hip_runtime.h>
#include <cmath>

#define B_    64
#define G_    8
#define E_    8
#define OC_   10
#define LL    4096
#define LP    4094
#define COMBINE_SIZE (B_ * G_ * OC_ * LP)   // 20,961,280

typedef float f32x4 __attribute__((ext_vector_type(4)));
typedef short s16x8 __attribute__((ext_vector_type(8)));

// round-to-nearest-even fp32 -> bf16 bits
__device__ __forceinline__ unsigned short f2bf(float f) {
    unsigned int u = __float_as_uint(f);
    unsigned int r = (u + 0x7FFFu + ((u >> 16) & 1u)) >> 16;
    return (unsigned short)r;
}

// LDS swizzle for the x-slab: XOR on dword index, bits 2..4.
// Depends only on l bits >=1 -> involution/bijective; spreads both the
// staging writes and the b128 fragment reads to 2 lanes/bank (free).
__device__ __forceinline__ int xswz(int l) {
    return ((((l >> 1) & 3) ^ ((l >> 6) & 3)) << 2) | (((l >> 8) & 1) << 4);
}

// fast tanh: 1 - 2/(e^{2v}+1); exp overflow/underflow saturates correctly
__device__ __forceinline__ float fast_tanh(float v) {
    const float e = __expf(2.f * v);
    return 1.f - 2.f * __builtin_amdgcn_rcpf(e + 1.f);
}

// ---- repack conv1 weights into MFMA A-fragment layout (bf16) -------------
// w1a[((g*3 + s)*64 + lane)*8 + j] = bf16(w1[g][o=lane&15][d=(lane>>4)*8+j][t=s])
// (rows o>=10 zero-padded)
__global__ void repack_w1a(const float* __restrict__ w1,
                           unsigned short* __restrict__ w1a) {
    const int t = blockIdx.x * 256 + threadIdx.x;   // over 8*3*64*8 = 12288
    if (t >= G_ * 3 * 64 * 8) return;
    const int g = t / 1536, r = t - g * 1536;
    const int s = r / 512,  q = r - s * 512;
    const int lane = q >> 3, j = q & 7;
    const int o = lane & 15, hi = lane >> 4;
    const int d = hi * 8 + j;
    unsigned short v = 0;
    if (o < OC_) v = f2bf(w1[g * 960 + o * 96 + d * 3 + s]);
    w1a[t] = v;
}

// ---------------- gating: logits -> softmax -> top2 -> gates --------------
__global__ void gate_kernel(const float* __restrict__ x,
                            const float* __restrict__ wg,
                            float* __restrict__ gws,    // [B,G,E] gates
                            float* __restrict__ gout) { // [B,E,G] output
    const int b   = blockIdx.x;
    const int tid = threadIdx.x;
    __shared__ float gin[G_ * 160];
    for (int i = tid; i < G_ * 160; i += 64) {
        int g = i / 160, r = i - g * 160;
        int d = r / 5,   t = r - d * 5;
        gin[i] = x[((size_t)b * 256 + g * 32 + d) * LL + (LL - 6 + t)];
    }
    __syncthreads();
    const int g = tid >> 3, e = tid & 7;
    const float* gp = gin + g * 160;
    const float* wp = wg + (size_t)g * 160 * E_ + e;
    float acc = 0.f;
    for (int i = 0; i < 160; ++i) acc = fmaf(gp[i], wp[i * E_], acc);

    float m = acc;
    #pragma unroll
    for (int s = 4; s >= 1; s >>= 1) m = fmaxf(m, __shfl_xor(m, s));
    float p = expf(acc - m);
    float sum = p;
    #pragma unroll
    for (int s = 4; s >= 1; s >>= 1) sum += __shfl_xor(sum, s);
    p /= sum;

    float pv[8];
    const int base = tid & ~7;
    #pragma unroll
    for (int j = 0; j < 8; ++j) pv[j] = __shfl(p, base + j);
    int i1 = 0; float v1 = pv[0];
    #pragma unroll
    for (int j = 1; j < 8; ++j) if (pv[j] > v1) { v1 = pv[j]; i1 = j; }
    int i2 = -1; float v2 = -1.f;
    #pragma unroll
    for (int j = 0; j < 8; ++j) if (j != i1 && pv[j] > v2) { v2 = pv[j]; i2 = j; }
    const float denom = v1 + v2 + 1e-6f;
    const float gate = (e == i1) ? v1 / denom : ((e == i2) ? v2 / denom : 0.f);
    gws[(b * G_ + g) * E_ + e]   = gate;
    gout[b * (E_ * G_) + e * G_ + g] = gate;
}

// ---------------- load-balancing loss (1 block, 64 threads) ---------------
__global__ void loss_kernel(const float* __restrict__ gws,
                            float* __restrict__ loss_out) {
    const int tid = threadIdx.x;   // tid = g*8 + e
    float imp = 0.f, ld = 0.f;
    for (int b = 0; b < B_; ++b) {
        const float v = gws[b * 64 + tid];
        imp += v;
        ld  += (v > 0.f) ? 1.f : 0.f;
    }
    float si = imp, sl = ld;
    #pragma unroll
    for (int msk = 1; msk <= 4; msk <<= 1) { si += __shfl_xor(si, msk); sl += __shfl_xor(sl, msk); }
    const float mi = si * 0.125f, ml = sl * 0.125f;
    float di = imp - mi, dl = ld - ml;
    float vi = di * di, vl = dl * dl;
    #pragma unroll
    for (int msk = 1; msk <= 4; msk <<= 1) { vi += __shfl_xor(vi, msk); vl += __shfl_xor(vl, msk); }
    const float cvi = (vi / 7.f) / (mi * mi + 1e-10f);
    const float cvl = (vl / 7.f) / (ml * ml + 1e-10f);
    float c = ((tid & 7) == 0) ? (cvi + cvl) : 0.f;
    #pragma unroll
    for (int msk = 1; msk < 64; msk <<= 1) c += __shfl_xor(c, msk);
    if (tid == 0) *loss_out = 0.01f * c;
}

// ---------------- MFMA conv1 -> tanh -> gated conv2 ------------------------
// grid: 4096 blocks = 512(bg) * 8(slab of 512 cols); 256 threads (4 waves).
// Stage x[32 d][514 l] transposed into LDS as bf16 [l][d-pairs] with XOR
// swizzle; each wave computes 8 16-col tiles via 3x mfma_f32_16x16x32_bf16
// (K=96, t=s planes), then tanh + 10x10 gated combine through a wave-private
// H tile in LDS (no cross-wave hazards after the single barrier).
__global__ __launch_bounds__(256) void conv_mfma(
        const float* __restrict__ x,
        const unsigned short* __restrict__ w1a,
        const float* __restrict__ b1,
        const float* __restrict__ w2, const float* __restrict__ b2,
        const float* __restrict__ gws,
        float* __restrict__ out) {
    const int tid  = threadIdx.x;
    const int slab = blockIdx.x & 7;
    const int bg   = blockIdx.x >> 3;
    const int g    = bg & 7;
    const int l0   = slab * 512;

    __shared__ char  xbytes[514 * 64];     // [l][32 bf16], XOR-swizzled
    __shared__ float Hl[4][16 * 12];       // per-wave H tile [col][m pad 12]
    __shared__ float weff[100];
    __shared__ float beff[10];

    // gated conv2 weights
    const float* gp = gws + bg * E_;
    if (tid < 100) {
        const int dd = tid / 10, j = tid - dd * 10;
        float s = 0.f;
        #pragma unroll
        for (int e = 0; e < 8; ++e)
            s = fmaf(gp[e], w2[(g * 80 + dd * 8 + e) * 10 + j], s);
        weff[tid] = s;
    } else if (tid < 110) {
        const int dd = tid - 100;
        float s = 0.f;
        #pragma unroll
        for (int e = 0; e < 8; ++e)
            s = fmaf(gp[e], b2[g * 80 + dd * 8 + e], s);
        beff[dd] = s;
    }

    // ---- stage x slab -> bf16 [l][d] (d-pairs packed in dwords) ----
    unsigned int* xw = reinterpret_cast<unsigned int*>(xbytes);
    {
        const int dp = tid >> 4;                 // d-pair 0..15
        const int lpart = (tid & 15) * 32;       // 32 cols per thread
        const float* r0 = x + ((size_t)bg * 32 + 2 * dp) * LL + l0 + lpart;
        const float* r1 = r0 + LL;
        #pragma unroll
        for (int i = 0; i < 32; i += 4) {
            float4 a = *reinterpret_cast<const float4*>(r0 + i);
            float4 c = *reinterpret_cast<const float4*>(r1 + i);
            #pragma unroll
            for (int k2 = 0; k2 < 4; ++k2) {
                const int l = lpart + i + k2;
                const unsigned int dw =
                    (unsigned int)f2bf(reinterpret_cast<const float*>(&a)[k2]) |
                    ((unsigned int)f2bf(reinterpret_cast<const float*>(&c)[k2]) << 16);
                xw[(16 * l + dp) ^ xswz(l)] = dw;
            }
        }
        if (tid < 16) {   // halo cols 512,513 (zero when out of range)
            #pragma unroll
            for (int l = 512; l < 514; ++l) {
                const int gc = l0 + l;
                float va = 0.f, vc = 0.f;
                if (gc < LL) {
                    va = x[((size_t)bg * 32 + 2 * tid) * LL + gc];
                    vc = x[((size_t)bg * 32 + 2 * tid + 1) * LL + gc];
                }
                const unsigned int dw = (unsigned int)f2bf(va) |
                                        ((unsigned int)f2bf(vc) << 16);
                xw[(16 * l + tid) ^ xswz(l)] = dw;   // xswz(512|513)==0 anyway
            }
        }
    }

    // ---- per-lane A fragments + bias ----
    const int lane = tid & 63, wq = tid >> 6;
    const int n = lane & 15, hi = lane >> 4;
    s16x8 afrag[3];
    {
        const uint4* w1a4 = reinterpret_cast<const uint4*>(w1a) + g * 192;
        #pragma unroll
        for (int s = 0; s < 3; ++s) {
            uint4 u = w1a4[s * 64 + lane];
            afrag[s] = *reinterpret_cast<s16x8*>(&u);
        }
    }
    const float* b1g = b1 + g * OC_;
    float b1v[4];
    #pragma unroll
    for (int r = 0; r < 4; ++r) {
        const int m = hi * 4 + r;
        b1v[r] = (m < OC_) ? b1g[m] : 0.f;
    }

    __syncthreads();

    float* Hw = Hl[wq];
    #pragma unroll 1
    for (int nt = 0; nt < 8; ++nt) {
        f32x4 acc = {b1v[0], b1v[1], b1v[2], b1v[3]};   // bias folded into C
        #pragma unroll
        for (int s = 0; s < 3; ++s) {
            const int l = wq * 128 + nt * 16 + n + s;
            const int ba = ((l << 6) | (hi << 4)) ^ (xswz(l) << 2);
            s16x8 bfrag = *reinterpret_cast<const s16x8*>(xbytes + ba);
            acc = __builtin_amdgcn_mfma_f32_16x16x32_bf16(afrag[s], bfrag, acc, 0, 0, 0);
        }
        // tanh -> wave-private H tile. Rows m = hi*4+r; hi==3 rows are pure
        // padding (m=12..15) and MUST NOT write (would alias column n+1).
        if (hi < 3) {
            float4 h;
            #pragma unroll
            for (int r = 0; r < 4; ++r)
                reinterpret_cast<float*>(&h)[r] = fast_tanh(acc[r]);
            *reinterpret_cast<float4*>(&Hw[n * 12 + hi * 4]) = h;
        }
        // same-wave ds_write -> ds_read; compiler inserts the lgkmcnt wait
        float hv[12];
        *reinterpret_cast<float4*>(&hv[0]) = *reinterpret_cast<const float4*>(&Hw[n * 12]);
        *reinterpret_cast<float4*>(&hv[4]) = *reinterpret_cast<const float4*>(&Hw[n * 12 + 4]);
        *reinterpret_cast<float4*>(&hv[8]) = *reinterpret_cast<const float4*>(&Hw[n * 12 + 8]);

        const int lcol = l0 + wq * 128 + nt * 16 + n;
        if (lcol < LP) {
            #pragma unroll
            for (int q = 0; q < 3; ++q) {
                const int dd = hi + 4 * q;
                if (dd < OC_) {
                    float r = beff[dd];
                    const float* wr = weff + dd * 10;
                    #pragma unroll
                    for (int j = 0; j < 10; ++j) r = fmaf(wr[j], hv[j], r);
                    out[(size_t)(bg * OC_ + dd) * LP + lcol] = r;
                }
            }
        }
    }
}

extern "C" void kernel_launch(void* const* d_in, const int* in_sizes, int n_in,
                              void* d_out, int out_size, void* d_ws, size_t ws_size,
                              hipStream_t stream) {
    (void)in_sizes; (void)n_in; (void)out_size; (void)ws_size;
    const float* x  = (const float*)d_in[0];
    const float* w1 = (const float*)d_in[1];
    const float* b1 = (const float*)d_in[2];
    const float* w2 = (const float*)d_in[3];
    const float* b2 = (const float*)d_in[4];
    const float* wg = (const float*)d_in[5];
    float* out      = (float*)d_out;
    float* gws      = (float*)d_ws;                                   // [B,G,E]
    unsigned short* w1a = (unsigned short*)((float*)d_ws + B_ * G_ * E_);
    float* loss_out = out + COMBINE_SIZE;
    float* gout     = out + COMBINE_SIZE + 1;

    repack_w1a<<<(G_ * 3 * 64 * 8 + 255) / 256, 256, 0, stream>>>(w1, w1a);
    gate_kernel<<<B_, 64, 0, stream>>>(x, wg, gws, gout);
    loss_kernel<<<1, 64, 0, stream>>>(gws, loss_out);
    conv_mfma<<<B_ * G_ * 8, 256, 0, stream>>>(x, w1a, b1, w2, b2, gws, out);
}

// Round 10
// 106.487 us; speedup vs baseline: 1.1069x; 1.1069x over previous
//
#include <hip/hip_runtime.h>
#include <cmath>

#define B_    64
#define G_    8
#define E_    8
#define OC_   10
#define LL    4096
#define LP    4094
#define COMBINE_SIZE (B_ * G_ * OC_ * LP)   // 20,961,280
#define SLOT  4104                          // 4096 + 8 pad floats per ring row

// fast tanh: 1 - 2/(e^{2v}+1); exp overflow/underflow saturates correctly
__device__ __forceinline__ float fast_tanh(float v) {
    const float e = __expf(2.f * v);
    return 1.f - 2.f * __builtin_amdgcn_rcpf(e + 1.f);
}

// granule (16B) swizzle within each 64-granule (1KB) chunk: involution
// c ^= (c>>3). Applied to the GLOBAL source of global_load_lds and to the
// LDS read offsets (both-sides rule); LDS destination stays linear.
__device__ __forceinline__ int gswz(int g) {
    const int c = g & 63;
    return (g & ~63) | (c ^ (c >> 3));
}

// ---- repack conv1 weights: w1[g][o][d][t] -> w1t[g][d][o*3+t] (row pad 32)
__global__ void repack_kernel(const float* __restrict__ w1,
                              float* __restrict__ w1t) {
    const int i = blockIdx.x * 256 + threadIdx.x;   // over 8*32*30
    if (i >= G_ * 32 * 30) return;
    const int g = i / 960, r = i - g * 960;
    const int d = r / 30,  s = r - d * 30;
    const int o = s / 3,   t = s - o * 3;
    w1t[g * 1024 + d * 32 + s] = w1[g * 960 + o * 96 + d * 3 + t];
}

// ---------------- gating: logits -> softmax -> top2 -> gates --------------
__global__ void gate_kernel(const float* __restrict__ x,
                            const float* __restrict__ wg,
                            float* __restrict__ gws,    // [B,G,E] gates
                            float* __restrict__ gout) { // [B,E,G] output
    const int b   = blockIdx.x;
    const int tid = threadIdx.x;
    __shared__ float gin[G_ * 160];
    for (int i = tid; i < G_ * 160; i += 64) {
        int g = i / 160, r = i - g * 160;
        int d = r / 5,   t = r - d * 5;
        gin[i] = x[((size_t)b * 256 + g * 32 + d) * LL + (LL - 6 + t)];
    }
    __syncthreads();
    const int g = tid >> 3, e = tid & 7;
    const float* gp = gin + g * 160;
    const float* wp = wg + (size_t)g * 160 * E_ + e;
    float acc = 0.f;
    for (int i = 0; i < 160; ++i) acc = fmaf(gp[i], wp[i * E_], acc);

    float m = acc;
    #pragma unroll
    for (int s = 4; s >= 1; s >>= 1) m = fmaxf(m, __shfl_xor(m, s));
    float p = expf(acc - m);
    float sum = p;
    #pragma unroll
    for (int s = 4; s >= 1; s >>= 1) sum += __shfl_xor(sum, s);
    p /= sum;

    float pv[8];
    const int base = tid & ~7;
    #pragma unroll
    for (int j = 0; j < 8; ++j) pv[j] = __shfl(p, base + j);
    int i1 = 0; float v1 = pv[0];
    #pragma unroll
    for (int j = 1; j < 8; ++j) if (pv[j] > v1) { v1 = pv[j]; i1 = j; }
    int i2 = -1; float v2 = -1.f;
    #pragma unroll
    for (int j = 0; j < 8; ++j) if (j != i1 && pv[j] > v2) { v2 = pv[j]; i2 = j; }
    const float denom = v1 + v2 + 1e-6f;
    const float gate = (e == i1) ? v1 / denom : ((e == i2) ? v2 / denom : 0.f);
    gws[(b * G_ + g) * E_ + e]   = gate;
    gout[b * (E_ * G_) + e * G_ + g] = gate;
}

// ---------------- load-balancing loss (1 block, 64 threads) ---------------
__global__ void loss_kernel(const float* __restrict__ gws,
                            float* __restrict__ loss_out) {
    const int tid = threadIdx.x;   // tid = g*8 + e
    float imp = 0.f, ld = 0.f;
    for (int b = 0; b < B_; ++b) {
        const float v = gws[b * 64 + tid];
        imp += v;
        ld  += (v > 0.f) ? 1.f : 0.f;
    }
    float si = imp, sl = ld;
    #pragma unroll
    for (int msk = 1; msk <= 4; msk <<= 1) { si += __shfl_xor(si, msk); sl += __shfl_xor(sl, msk); }
    const float mi = si * 0.125f, ml = sl * 0.125f;
    float di = imp - mi, dl = ld - ml;
    float vi = di * di, vl = dl * dl;
    #pragma unroll
    for (int msk = 1; msk <= 4; msk <<= 1) { vi += __shfl_xor(vi, msk); vl += __shfl_xor(vl, msk); }
    const float cvi = (vi / 7.f) / (mi * mi + 1e-10f);
    const float cvl = (vl / 7.f) / (ml * ml + 1e-10f);
    float c = ((tid & 7) == 0) ? (cvi + cvl) : 0.f;
    #pragma unroll
    for (int msk = 1; msk < 64; msk <<= 1) c += __shfl_xor(c, msk);
    if (tid == 0) *loss_out = 0.01f * c;
}

// ---------------- main fused conv1 -> tanh -> gated conv2 ------------------
// One block per (b,g): 512 blocks x 512 threads (8 waves), 8 l per thread.
// T3/T4 counted-vmcnt pipeline: LDS ring of 4 row-buffers; row d+3 staged
// via global_load_lds (2 per wave) with pre-swizzled global source; per row
// exactly one raw s_barrier and one s_waitcnt vmcnt(4) (never drained to 0
// in steady state). Weights stay wave-uniform scalar loads.
__global__ __launch_bounds__(512) void conv_kernel(
        const float* __restrict__ x,
        const float* __restrict__ w1t,   // repacked [g][d][32]
        const float* __restrict__ b1,
        const float* __restrict__ w2, const float* __restrict__ b2,
        const float* __restrict__ gws,
        float* __restrict__ out) {
    const int tid  = threadIdx.x;
    const int lane = tid & 63;
    const int wq   = tid >> 6;           // wave id 0..7
    const int bg   = blockIdx.x;         // b*8 + g
    const int g    = bg & 7;

    __shared__ float ring[4][SLOT];
    __shared__ float weff[OC_ * OC_];    // [dd][j]
    __shared__ float beff[OC_];

    // zero the 8-float tail pad of each ring slot (read by last thread only)
    if (tid < 32) ring[tid >> 3][4096 + (tid & 7)] = 0.f;

    const float* gp = gws + bg * E_;
    if (tid < 100) {
        const int dd = tid / 10, j = tid - dd * 10;
        float s = 0.f;
        #pragma unroll
        for (int e = 0; e < 8; ++e)
            s = fmaf(gp[e], w2[(g * 80 + dd * 8 + e) * 10 + j], s);
        weff[tid] = s;
    } else if (tid < 110) {
        const int dd = tid - 100;
        float s = 0.f;
        #pragma unroll
        for (int e = 0; e < 8; ++e)
            s = fmaf(gp[e], b2[g * 80 + dd * 8 + e], s);
        beff[dd] = s;
    }
    __syncthreads();

    const float* xrow = x + (size_t)bg * 32 * LL;   // 32 contiguous rows
    const float* wgt  = w1t + g * 1024;             // wave-uniform base
    const float* b1g  = b1 + g * OC_;               // wave-uniform

    // per-lane swizzled source offset within a 1KB chunk (floats)
    const int sl = (lane ^ (lane >> 3)) * 4;

#define STAGE(r)                                                              \
    {                                                                         \
        const float* gb = xrow + (size_t)(r) * LL + (wq * 2) * 256;           \
        float* lb = &ring[(r) & 3][(wq * 2) * 256];                           \
        __builtin_amdgcn_global_load_lds(                                     \
            (const __attribute__((address_space(1))) void*)(gb + sl),         \
            (__attribute__((address_space(3))) void*)lb, 16, 0, 0);           \
        __builtin_amdgcn_global_load_lds(                                     \
            (const __attribute__((address_space(1))) void*)(gb + 256 + sl),   \
            (__attribute__((address_space(3))) void*)(lb + 256), 16, 0, 0);   \
    }

#define WAITV(n) asm volatile("s_waitcnt vmcnt(" #n ")" ::: "memory");

    float acc[10][8];
    #pragma unroll
    for (int o = 0; o < 10; ++o) {
        const float bv = b1g[o];
        #pragma unroll
        for (int k = 0; k < 8; ++k) acc[o][k] = bv;
    }

    // fixed swizzled read offsets (floats) for this thread's 10-float window
    const int p1 = gswz(tid * 2) * 4;
    const int p2 = gswz(tid * 2 + 1) * 4;
    const int p3 = gswz(tid * 2 + 2) * 4;

#define COMPROW(dd)                                                           \
    {                                                                         \
        const float* sb = ring[(dd) & 3];                                     \
        float xw[10];                                                         \
        *reinterpret_cast<float4*>(&xw[0]) =                                  \
            *reinterpret_cast<const float4*>(sb + p1);                        \
        *reinterpret_cast<float4*>(&xw[4]) =                                  \
            *reinterpret_cast<const float4*>(sb + p2);                        \
        const float2 t2 = *reinterpret_cast<const float2*>(sb + p3);          \
        xw[8] = t2.x; xw[9] = t2.y;                                           \
        const float* wr = wgt + (dd) * 32;                                    \
        _Pragma("unroll")                                                     \
        for (int o = 0; o < 10; ++o) {                                        \
            const float w0 = wr[o * 3];                                       \
            const float wA = wr[o * 3 + 1];                                   \
            const float wB = wr[o * 3 + 2];                                   \
            _Pragma("unroll")                                                 \
            for (int k = 0; k < 8; ++k)                                       \
                acc[o][k] = fmaf(xw[k + 2], wB,                               \
                            fmaf(xw[k + 1], wA,                              \
                            fmaf(xw[k],     w0, acc[o][k])));                 \
        }                                                                     \
    }

    // prologue: stage rows 0..2 (6 loads in flight per wave)
    STAGE(0) STAGE(1) STAGE(2)

    #pragma unroll 1
    for (int d = 0; d < 30; ++d) {
        WAITV(4)                              // row d's 2 loads complete
        __builtin_amdgcn_s_barrier();         // all waves' chunks arrived
        if (d < 29) STAGE(d + 3)              // refill (slot (d+3)&3 is free)
        COMPROW(d)
    }
    WAITV(2)
    __builtin_amdgcn_s_barrier();
    COMPROW(30)
    WAITV(0)
    __builtin_amdgcn_s_barrier();
    COMPROW(31)

#undef STAGE
#undef WAITV
#undef COMPROW

    #pragma unroll
    for (int o = 0; o < 10; ++o)
        #pragma unroll
        for (int k = 0; k < 8; ++k)
            acc[o][k] = fast_tanh(acc[o][k]);

    const int l = tid * 8;
    float* ob = out + (size_t)bg * OC_ * LP + l;
    const bool full = (l + 8 <= LP);
    #pragma unroll
    for (int dd = 0; dd < 10; ++dd) {
        const float* wr = weff + dd * 10;
        float r[8];
        const float bv = beff[dd];
        #pragma unroll
        for (int k = 0; k < 8; ++k) r[k] = bv;
        #pragma unroll
        for (int j = 0; j < 10; ++j) {
            const float w = wr[j];
            #pragma unroll
            for (int k = 0; k < 8; ++k) r[k] = fmaf(acc[j][k], w, r[k]);
        }
        float* op = ob + (size_t)dd * LP;
        if (full) {
            *reinterpret_cast<float2*>(op)     = make_float2(r[0], r[1]);
            *reinterpret_cast<float2*>(op + 2) = make_float2(r[2], r[3]);
            *reinterpret_cast<float2*>(op + 4) = make_float2(r[4], r[5]);
            *reinterpret_cast<float2*>(op + 6) = make_float2(r[6], r[7]);
        } else {
            #pragma unroll
            for (int k = 0; k < 8; ++k)
                if (l + k < LP) op[k] = r[k];
        }
    }
}

extern "C" void kernel_launch(void* const* d_in, const int* in_sizes, int n_in,
                              void* d_out, int out_size, void* d_ws, size_t ws_size,
                              hipStream_t stream) {
    (void)in_sizes; (void)n_in; (void)out_size; (void)ws_size;
    const float* x  = (const float*)d_in[0];
    const float* w1 = (const float*)d_in[1];
    const float* b1 = (const float*)d_in[2];
    const float* w2 = (const float*)d_in[3];
    const float* b2 = (const float*)d_in[4];
    const float* wg = (const float*)d_in[5];
    float* out      = (float*)d_out;
    float* gws      = (float*)d_ws;                         // [B,G,E]
    float* w1t      = (float*)d_ws + B_ * G_ * E_;          // [g][d][32]
    float* loss_out = out + COMBINE_SIZE;
    float* gout     = out + COMBINE_SIZE + 1;

    repack_kernel<<<(G_ * 32 * 30 + 255) / 256, 256, 0, stream>>>(w1, w1t);
    gate_kernel<<<B_, 64, 0, stream>>>(x, wg, gws, gout);
    loss_kernel<<<1, 64, 0, stream>>>(gws, loss_out);
    conv_kernel<<<B_ * G_, 512, 0, stream>>>(x, w1t, b1, w2, b2, gws, out);
}

// Round 11
// 102.159 us; speedup vs baseline: 1.1538x; 1.0424x over previous
//
#include <hip/hip_runtime.h>
#include <cmath>

#define B_    64
#define G_    8
#define E_    8
#define OC_   10
#define LL    4096
#define LP    4094
#define COMBINE_SIZE (B_ * G_ * OC_ * LP)   // 20,961,280
#define SLOT  4096                          // floats per ring row

// fast tanh: 1 - 2/(e^{2v}+1); exp overflow/underflow saturates correctly
__device__ __forceinline__ float fast_tanh(float v) {
    const float e = __expf(2.f * v);
    return 1.f - 2.f * __builtin_amdgcn_rcpf(e + 1.f);
}

// granule (16B) swizzle within each 64-granule (1KB) chunk: involution
// c ^= (c>>3). Applied to the GLOBAL source of global_load_lds and to the
// LDS read offsets (both-sides rule); LDS destination stays linear.
__device__ __forceinline__ int gswz(int g) {
    const int c = g & 63;
    return (g & ~63) | (c ^ (c >> 3));
}

// ---- repack conv1 weights: w1[g][o][d][t] -> w1t[g][d][o*3+t] (row pad 32)
__global__ void repack_kernel(const float* __restrict__ w1,
                              float* __restrict__ w1t) {
    const int i = blockIdx.x * 256 + threadIdx.x;   // over 8*32*30
    if (i >= G_ * 32 * 30) return;
    const int g = i / 960, r = i - g * 960;
    const int d = r / 30,  s = r - d * 30;
    const int o = s / 3,   t = s - o * 3;
    w1t[g * 1024 + d * 32 + s] = w1[g * 960 + o * 96 + d * 3 + t];
}

// ---------------- load-balancing loss (1 block, 64 threads) ---------------
__global__ void loss_kernel(const float* __restrict__ gws,
                            float* __restrict__ loss_out) {
    const int tid = threadIdx.x;   // tid = g*8 + e
    float imp = 0.f, ld = 0.f;
    for (int b = 0; b < B_; ++b) {
        const float v = gws[b * 64 + tid];
        imp += v;
        ld  += (v > 0.f) ? 1.f : 0.f;
    }
    float si = imp, sl = ld;
    #pragma unroll
    for (int msk = 1; msk <= 4; msk <<= 1) { si += __shfl_xor(si, msk); sl += __shfl_xor(sl, msk); }
    const float mi = si * 0.125f, ml = sl * 0.125f;
    float di = imp - mi, dl = ld - ml;
    float vi = di * di, vl = dl * dl;
    #pragma unroll
    for (int msk = 1; msk <= 4; msk <<= 1) { vi += __shfl_xor(vi, msk); vl += __shfl_xor(vl, msk); }
    const float cvi = (vi / 7.f) / (mi * mi + 1e-10f);
    const float cvl = (vl / 7.f) / (ml * ml + 1e-10f);
    float c = ((tid & 7) == 0) ? (cvi + cvl) : 0.f;
    #pragma unroll
    for (int msk = 1; msk < 64; msk <<= 1) c += __shfl_xor(c, msk);
    if (tid == 0) *loss_out = 0.01f * c;
}

// ---------------- fused gating + conv1 -> tanh -> gated conv2 --------------
// One block per (b,g): 512 blocks x 512 threads (8 waves), 8 l per thread.
// BARRIER-FREE counted-vmcnt pipeline: each wave stages only its own
// 512-float span per row (2x global_load_lds), so per-wave vmcnt(4) is the
// only synchronization; waves free-run 3 rows deep. Cross-thread halo via
// __shfl_down; lane-63 halo from a wave-private LDS table preloaded once.
// Gating (softmax+top2) computed in the prologue by wave 0; writes gws/gout.
__global__ __launch_bounds__(512, 4) void conv_kernel(
        const float* __restrict__ x,
        const float* __restrict__ w1t,   // repacked [g][d][32]
        const float* __restrict__ b1,
        const float* __restrict__ w2, const float* __restrict__ b2,
        const float* __restrict__ wg,
        float* __restrict__ out,
        float* __restrict__ gws,         // [B*G, E] gates for loss_kernel
        float* __restrict__ gout) {      // [B, E, G] gates output
    const int tid  = threadIdx.x;
    const int lane = tid & 63;
    const int wq   = tid >> 6;           // wave id 0..7
    const int bg   = blockIdx.x;         // b*8 + g
    const int g    = bg & 7;
    const int b    = bg >> 3;

    __shared__ float  ring[4][SLOT];
    __shared__ float2 halo[8][32];       // [wave][row] lane-63 halo pair
    __shared__ float  gin[160];
    __shared__ float  gg[E_];
    __shared__ float  weff[OC_ * OC_];   // [dd][j]
    __shared__ float  beff[OC_];

    const float* xrow = x + (size_t)bg * 32 * LL;   // this block's 32 rows

    // ---- gating input (last-6..last-1 cols of each of the 32 rows) ----
    if (tid < 160) {
        const int d = tid / 5, t = tid - 5 * d;
        gin[tid] = xrow[(size_t)d * LL + (LL - 6 + t)];
    }
    __syncthreads();

    if (tid < 64) {
        const int e = tid & 7, part = tid >> 3;
        const float* wp = wg + g * 1280 + e;
        float logit = 0.f;
        #pragma unroll
        for (int i = 0; i < 20; ++i) {
            const int idx = part * 20 + i;
            logit = fmaf(gin[idx], wp[idx * 8], logit);
        }
        logit += __shfl_xor(logit, 8);
        logit += __shfl_xor(logit, 16);
        logit += __shfl_xor(logit, 32);
        // lanes 0-7 now hold full logits for e=0..7; softmax over them
        float m = logit;
        #pragma unroll
        for (int s = 4; s >= 1; s >>= 1) m = fmaxf(m, __shfl_xor(m, s));
        float p = expf(logit - m);
        float sum = p;
        #pragma unroll
        for (int s = 4; s >= 1; s >>= 1) sum += __shfl_xor(sum, s);
        p /= sum;
        if (tid < 8) {
            float pv[8];
            #pragma unroll
            for (int j = 0; j < 8; ++j) pv[j] = __shfl(p, j);
            int i1 = 0; float v1 = pv[0];
            #pragma unroll
            for (int j = 1; j < 8; ++j) if (pv[j] > v1) { v1 = pv[j]; i1 = j; }
            int i2 = -1; float v2 = -1.f;
            #pragma unroll
            for (int j = 0; j < 8; ++j) if (j != i1 && pv[j] > v2) { v2 = pv[j]; i2 = j; }
            const float denom = v1 + v2 + 1e-6f;
            const float gate = (e == i1) ? v1 / denom
                             : ((e == i2) ? v2 / denom : 0.f);
            gg[e] = gate;
            gws[bg * E_ + e] = gate;
            gout[b * 64 + e * 8 + g] = gate;
        }
    }
    // wave-private lane-63 halo table: halo[wq][row] = x[row][wq*512+512,+513]
    if (lane < 32) {
        const float* hp = xrow + (size_t)lane * LL + (wq < 7 ? wq * 512 + 512 : 0);
        halo[wq][lane] = *reinterpret_cast<const float2*>(hp);
    }
    __syncthreads();

    // gated conv2 weights from gg
    if (tid < 100) {
        const int dd = tid / 10, j = tid - dd * 10;
        float s = 0.f;
        #pragma unroll
        for (int e = 0; e < 8; ++e)
            s = fmaf(gg[e], w2[(g * 80 + dd * 8 + e) * 10 + j], s);
        weff[tid] = s;
    } else if (tid < 110) {
        const int dd = tid - 100;
        float s = 0.f;
        #pragma unroll
        for (int e = 0; e < 8; ++e)
            s = fmaf(gg[e], b2[g * 80 + dd * 8 + e], s);
        beff[dd] = s;
    }
    // NOTE: weff/beff are only read in the epilogue; a __syncthreads after
    // the main loop (before the epilogue) publishes them.

    const float* wgt = w1t + g * 1024;          // wave-uniform base
    const float* b1g = b1 + g * OC_;            // wave-uniform

    // per-lane swizzled source offset within this wave's 1KB chunks (floats)
    const int sl = (lane ^ (lane >> 3)) * 4;

#define STAGE(r)                                                              \
    {                                                                         \
        const float* gb = xrow + (size_t)(r) * LL + wq * 512;                 \
        float* lb = &ring[(r) & 3][wq * 512];                                 \
        __builtin_amdgcn_global_load_lds(                                     \
            (const __attribute__((address_space(1))) void*)(gb + sl),         \
            (__attribute__((address_space(3))) void*)lb, 16, 0, 0);           \
        __builtin_amdgcn_global_load_lds(                                     \
            (const __attribute__((address_space(1))) void*)(gb + 256 + sl),   \
            (__attribute__((address_space(3))) void*)(lb + 256), 16, 0, 0);   \
    }

#define WAITV(n) asm volatile("s_waitcnt vmcnt(" #n ")" ::: "memory");

    float acc[10][8];
    #pragma unroll
    for (int o = 0; o < 10; ++o) {
        const float bv = b1g[o];
        #pragma unroll
        for (int k = 0; k < 8; ++k) acc[o][k] = bv;
    }

    // fixed swizzled read offsets (floats) for this thread's 8-float window
    const int p1 = gswz(tid * 2) * 4;
    const int p2 = gswz(tid * 2 + 1) * 4;
    const bool l63 = (lane == 63);

#define COMPROW(dd)                                                           \
    {                                                                         \
        const float* sb = ring[(dd) & 3];                                     \
        float xw[10];                                                         \
        *reinterpret_cast<float4*>(&xw[0]) =                                  \
            *reinterpret_cast<const float4*>(sb + p1);                        \
        *reinterpret_cast<float4*>(&xw[4]) =                                  \
            *reinterpret_cast<const float4*>(sb + p2);                        \
        const float2 hv = halo[wq][(dd)];                                     \
        const float n0 = __shfl_down(xw[0], 1);                               \
        const float n1 = __shfl_down(xw[1], 1);                               \
        xw[8] = l63 ? hv.x : n0;                                              \
        xw[9] = l63 ? hv.y : n1;                                              \
        const float* wr = wgt + (dd) * 32;                                    \
        _Pragma("unroll")                                                     \
        for (int o = 0; o < 10; ++o) {                                        \
            const float w0 = wr[o * 3];                                       \
            const float wA = wr[o * 3 + 1];                                   \
            const float wB = wr[o * 3 + 2];                                   \
            _Pragma("unroll")                                                 \
            for (int k = 0; k < 8; ++k)                                       \
                acc[o][k] = fmaf(xw[k + 2], wB,                               \
                            fmaf(xw[k + 1], wA,                              \
                            fmaf(xw[k],     w0, acc[o][k])));                 \
        }                                                                     \
    }

    // prologue: stage rows 0..2 (6 wave-private loads in flight)
    STAGE(0) STAGE(1) STAGE(2)

    #pragma unroll 1
    for (int d = 0; d < 29; ++d) {
        WAITV(4)              // this wave's row-d loads complete
        COMPROW(d)
        STAGE(d + 3)          // refill; slot (d+3)&3 was consumed at d-1
    }
    WAITV(4) COMPROW(29)
    WAITV(2) COMPROW(30)
    WAITV(0) COMPROW(31)

#undef STAGE
#undef WAITV
#undef COMPROW

    #pragma unroll
    for (int o = 0; o < 10; ++o)
        #pragma unroll
        for (int k = 0; k < 8; ++k)
            acc[o][k] = fast_tanh(acc[o][k]);

    __syncthreads();   // publish weff/beff (written in prologue)

    const int l = tid * 8;
    float* ob = out + (size_t)bg * OC_ * LP + l;
    const bool full = (l + 8 <= LP);
    #pragma unroll
    for (int dd = 0; dd < 10; ++dd) {
        const float* wr = weff + dd * 10;
        float r[8];
        const float bv = beff[dd];
        #pragma unroll
        for (int k = 0; k < 8; ++k) r[k] = bv;
        #pragma unroll
        for (int j = 0; j < 10; ++j) {
            const float w = wr[j];
            #pragma unroll
            for (int k = 0; k < 8; ++k) r[k] = fmaf(acc[j][k], w, r[k]);
        }
        float* op = ob + (size_t)dd * LP;
        if (full) {
            *reinterpret_cast<float2*>(op)     = make_float2(r[0], r[1]);
            *reinterpret_cast<float2*>(op + 2) = make_float2(r[2], r[3]);
            *reinterpret_cast<float2*>(op + 4) = make_float2(r[4], r[5]);
            *reinterpret_cast<float2*>(op + 6) = make_float2(r[6], r[7]);
        } else {
            #pragma unroll
            for (int k = 0; k < 8; ++k)
                if (l + k < LP) op[k] = r[k];
        }
    }
}

extern "C" void kernel_launch(void* const* d_in, const int* in_sizes, int n_in,
                              void* d_out, int out_size, void* d_ws, size_t ws_size,
                              hipStream_t stream) {
    (void)in_sizes; (void)n_in; (void)out_size; (void)ws_size;
    const float* x  = (const float*)d_in[0];
    const float* w1 = (const float*)d_in[1];
    const float* b1 = (const float*)d_in[2];
    const float* w2 = (const float*)d_in[3];
    const float* b2 = (const float*)d_in[4];
    const float* wg = (const float*)d_in[5];
    float* out      = (float*)d_out;
    float* gws      = (float*)d_ws;                         // [B,G,E]
    float* w1t      = (float*)d_ws + B_ * G_ * E_;          // [g][d][32]
    float* loss_out = out + COMBINE_SIZE;
    float* gout     = out + COMBINE_SIZE + 1;

    repack_kernel<<<(G_ * 32 * 30 + 255) / 256, 256, 0, stream>>>(w1, w1t);
    conv_kernel<<<B_ * G_, 512, 0, stream>>>(x, w1t, b1, w2, b2, wg,
                                             out, gws, gout);
    loss_kernel<<<1, 64, 0, stream>>>(gws, loss_out);
}

// Round 12
// 100.042 us; speedup vs baseline: 1.1782x; 1.0212x over previous
//
#include <hip/hip_runtime.h>
#include <cmath>

#define B_    64
#define G_    8
#define E_    8
#define OC_   10
#define LL    4096
#define LP    4094
#define COMBINE_SIZE (B_ * G_ * OC_ * LP)   // 20,961,280
#define SLOT  4096                          // floats per ring row

typedef float f32x2 __attribute__((ext_vector_type(2)));

// fast tanh: 1 - 2/(e^{2v}+1); exp overflow/underflow saturates correctly
__device__ __forceinline__ float fast_tanh(float v) {
    const float e = __expf(2.f * v);
    return 1.f - 2.f * __builtin_amdgcn_rcpf(e + 1.f);
}

// granule (16B) swizzle within each 64-granule (1KB) chunk: involution
// c ^= (c>>3). Applied to the GLOBAL source of global_load_lds and to the
// LDS read offsets (both-sides rule); LDS destination stays linear.
__device__ __forceinline__ int gswz(int g) {
    const int c = g & 63;
    return (g & ~63) | (c ^ (c >> 3));
}

// ---- repack conv1 weights: w1[g][o][d][t] -> w1t[g][d][o*3+t] (row pad 32)
__global__ void repack_kernel(const float* __restrict__ w1,
                              float* __restrict__ w1t) {
    const int i = blockIdx.x * 256 + threadIdx.x;   // over 8*32*30
    if (i >= G_ * 32 * 30) return;
    const int g = i / 960, r = i - g * 960;
    const int d = r / 30,  s = r - d * 30;
    const int o = s / 3,   t = s - o * 3;
    w1t[g * 1024 + d * 32 + s] = w1[g * 960 + o * 96 + d * 3 + t];
}

// ---------------- load-balancing loss (1 block, 64 threads) ---------------
__global__ void loss_kernel(const float* __restrict__ gws,
                            float* __restrict__ loss_out) {
    const int tid = threadIdx.x;   // tid = g*8 + e
    float imp = 0.f, ld = 0.f;
    for (int b = 0; b < B_; ++b) {
        const float v = gws[b * 64 + tid];
        imp += v;
        ld  += (v > 0.f) ? 1.f : 0.f;
    }
    float si = imp, sl = ld;
    #pragma unroll
    for (int msk = 1; msk <= 4; msk <<= 1) { si += __shfl_xor(si, msk); sl += __shfl_xor(sl, msk); }
    const float mi = si * 0.125f, ml = sl * 0.125f;
    float di = imp - mi, dl = ld - ml;
    float vi = di * di, vl = dl * dl;
    #pragma unroll
    for (int msk = 1; msk <= 4; msk <<= 1) { vi += __shfl_xor(vi, msk); vl += __shfl_xor(vl, msk); }
    const float cvi = (vi / 7.f) / (mi * mi + 1e-10f);
    const float cvl = (vl / 7.f) / (ml * ml + 1e-10f);
    float c = ((tid & 7) == 0) ? (cvi + cvl) : 0.f;
    #pragma unroll
    for (int msk = 1; msk < 64; msk <<= 1) c += __shfl_xor(c, msk);
    if (tid == 0) *loss_out = 0.01f * c;
}

// ---------------- fused gating + conv1 -> tanh -> gated conv2 --------------
// One block per (b,g): 512 blocks x 512 threads (8 waves), 8 l per thread.
// BARRIER-FREE counted-vmcnt pipeline (per-wave-private spans, vmcnt(4)).
// Inner loop uses 2-wide packed fp32 math (v_pk_fma_f32) to halve VALU
// issue: acc held as f32x2 pairs over the k dimension.
__global__ __launch_bounds__(512, 4) void conv_kernel(
        const float* __restrict__ x,
        const float* __restrict__ w1t,   // repacked [g][d][32]
        const float* __restrict__ b1,
        const float* __restrict__ w2, const float* __restrict__ b2,
        const float* __restrict__ wg,
        float* __restrict__ out,
        float* __restrict__ gws,         // [B*G, E] gates for loss_kernel
        float* __restrict__ gout) {      // [B, E, G] gates output
    const int tid  = threadIdx.x;
    const int lane = tid & 63;
    const int wq   = tid >> 6;           // wave id 0..7
    const int bg   = blockIdx.x;         // b*8 + g
    const int g    = bg & 7;
    const int b    = bg >> 3;

    __shared__ float  ring[4][SLOT];
    __shared__ float2 halo[8][32];       // [wave][row] lane-63 halo pair
    __shared__ float  gin[160];
    __shared__ float  gg[E_];
    __shared__ float  weff[OC_ * OC_];   // [dd][j]
    __shared__ float  beff[OC_];

    const float* xrow = x + (size_t)bg * 32 * LL;   // this block's 32 rows

    // ---- gating input (last-6..last-1 cols of each of the 32 rows) ----
    if (tid < 160) {
        const int d = tid / 5, t = tid - 5 * d;
        gin[tid] = xrow[(size_t)d * LL + (LL - 6 + t)];
    }
    __syncthreads();

    if (tid < 64) {
        const int e = tid & 7, part = tid >> 3;
        const float* wp = wg + g * 1280 + e;
        float logit = 0.f;
        #pragma unroll
        for (int i = 0; i < 20; ++i) {
            const int idx = part * 20 + i;
            logit = fmaf(gin[idx], wp[idx * 8], logit);
        }
        logit += __shfl_xor(logit, 8);
        logit += __shfl_xor(logit, 16);
        logit += __shfl_xor(logit, 32);
        // lanes 0-7 now hold full logits for e=0..7; softmax over them
        float m = logit;
        #pragma unroll
        for (int s = 4; s >= 1; s >>= 1) m = fmaxf(m, __shfl_xor(m, s));
        float p = expf(logit - m);
        float sum = p;
        #pragma unroll
        for (int s = 4; s >= 1; s >>= 1) sum += __shfl_xor(sum, s);
        p /= sum;
        if (tid < 8) {
            float pv[8];
            #pragma unroll
            for (int j = 0; j < 8; ++j) pv[j] = __shfl(p, j);
            int i1 = 0; float v1 = pv[0];
            #pragma unroll
            for (int j = 1; j < 8; ++j) if (pv[j] > v1) { v1 = pv[j]; i1 = j; }
            int i2 = -1; float v2 = -1.f;
            #pragma unroll
            for (int j = 0; j < 8; ++j) if (j != i1 && pv[j] > v2) { v2 = pv[j]; i2 = j; }
            const float denom = v1 + v2 + 1e-6f;
            const float gate = (e == i1) ? v1 / denom
                             : ((e == i2) ? v2 / denom : 0.f);
            gg[e] = gate;
            gws[bg * E_ + e] = gate;
            gout[b * 64 + e * 8 + g] = gate;
        }
    }
    // wave-private lane-63 halo table: halo[wq][row] = x[row][wq*512+512,+513]
    if (lane < 32) {
        const float* hp = xrow + (size_t)lane * LL + (wq < 7 ? wq * 512 + 512 : 0);
        halo[wq][lane] = *reinterpret_cast<const float2*>(hp);
    }
    __syncthreads();

    // gated conv2 weights from gg
    if (tid < 100) {
        const int dd = tid / 10, j = tid - dd * 10;
        float s = 0.f;
        #pragma unroll
        for (int e = 0; e < 8; ++e)
            s = fmaf(gg[e], w2[(g * 80 + dd * 8 + e) * 10 + j], s);
        weff[tid] = s;
    } else if (tid < 110) {
        const int dd = tid - 100;
        float s = 0.f;
        #pragma unroll
        for (int e = 0; e < 8; ++e)
            s = fmaf(gg[e], b2[g * 80 + dd * 8 + e], s);
        beff[dd] = s;
    }
    // weff/beff published by the __syncthreads after the main loop.

    const float* wgt = w1t + g * 1024;          // wave-uniform base
    const float* b1g = b1 + g * OC_;            // wave-uniform

    // per-lane swizzled source offset within this wave's 1KB chunks (floats)
    const int sl = (lane ^ (lane >> 3)) * 4;

#define STAGE(r)                                                              \
    {                                                                         \
        const float* gb = xrow + (size_t)(r) * LL + wq * 512;                 \
        float* lb = &ring[(r) & 3][wq * 512];                                 \
        __builtin_amdgcn_global_load_lds(                                     \
            (const __attribute__((address_space(1))) void*)(gb + sl),         \
            (__attribute__((address_space(3))) void*)lb, 16, 0, 0);           \
        __builtin_amdgcn_global_load_lds(                                     \
            (const __attribute__((address_space(1))) void*)(gb + 256 + sl),   \
            (__attribute__((address_space(3))) void*)(lb + 256), 16, 0, 0);   \
    }

#define WAITV(n) asm volatile("s_waitcnt vmcnt(" #n ")" ::: "memory");

    // packed accumulators: acc2[o][q] covers k = 2q, 2q+1
    f32x2 acc2[10][4];
    #pragma unroll
    for (int o = 0; o < 10; ++o) {
        const float bv = b1g[o];
        #pragma unroll
        for (int q = 0; q < 4; ++q) acc2[o][q] = (f32x2){bv, bv};
    }

    // fixed swizzled read offsets (floats) for this thread's 8-float window
    const int p1 = gswz(tid * 2) * 4;
    const int p2 = gswz(tid * 2 + 1) * 4;
    const bool l63 = (lane == 63);

#define COMPROW(dd)                                                           \
    {                                                                         \
        const float* sb = ring[(dd) & 3];                                     \
        float xw[10];                                                         \
        *reinterpret_cast<float4*>(&xw[0]) =                                  \
            *reinterpret_cast<const float4*>(sb + p1);                        \
        *reinterpret_cast<float4*>(&xw[4]) =                                  \
            *reinterpret_cast<const float4*>(sb + p2);                        \
        const float2 hv = halo[wq][(dd)];                                     \
        const float n0 = __shfl_down(xw[0], 1);                               \
        const float n1 = __shfl_down(xw[1], 1);                               \
        xw[8] = l63 ? hv.x : n0;                                              \
        xw[9] = l63 ? hv.y : n1;                                              \
        f32x2 xv[5], xb[4];                                                   \
        _Pragma("unroll")                                                     \
        for (int q = 0; q < 5; ++q) xv[q] = (f32x2){xw[2*q], xw[2*q+1]};      \
        _Pragma("unroll")                                                     \
        for (int q = 0; q < 4; ++q) xb[q] = (f32x2){xw[2*q+1], xw[2*q+2]};    \
        const float* wr = wgt + (dd) * 32;                                    \
        _Pragma("unroll")                                                     \
        for (int o = 0; o < 10; ++o) {                                        \
            const float w0 = wr[o * 3];                                       \
            const float wA = wr[o * 3 + 1];                                   \
            const float wB = wr[o * 3 + 2];                                   \
            const f32x2 W0 = {w0, w0}, WA = {wA, wA}, WB = {wB, wB};          \
            _Pragma("unroll")                                                 \
            for (int q = 0; q < 4; ++q)                                       \
                acc2[o][q] = __builtin_elementwise_fma(xv[q + 1], WB,         \
                             __builtin_elementwise_fma(xb[q],     WA,         \
                             __builtin_elementwise_fma(xv[q],     W0,         \
                                                       acc2[o][q])));         \
        }                                                                     \
    }

    // prologue: stage rows 0..2 (6 wave-private loads in flight)
    STAGE(0) STAGE(1) STAGE(2)

    #pragma unroll 1
    for (int d = 0; d < 29; ++d) {
        WAITV(4)              // this wave's row-d loads complete
        COMPROW(d)
        STAGE(d + 3)          // refill; slot (d+3)&3 was consumed at d-1
    }
    WAITV(4) COMPROW(29)
    WAITV(2) COMPROW(30)
    WAITV(0) COMPROW(31)

#undef STAGE
#undef WAITV
#undef COMPROW

    #pragma unroll
    for (int o = 0; o < 10; ++o)
        #pragma unroll
        for (int q = 0; q < 4; ++q) {
            acc2[o][q][0] = fast_tanh(acc2[o][q][0]);
            acc2[o][q][1] = fast_tanh(acc2[o][q][1]);
        }

    __syncthreads();   // publish weff/beff (written in prologue)

    const int l = tid * 8;
    float* ob = out + (size_t)bg * OC_ * LP + l;
    const bool full = (l + 8 <= LP);
    #pragma unroll
    for (int dd = 0; dd < 10; ++dd) {
        const float* wr = weff + dd * 10;
        const float bv = beff[dd];
        f32x2 r2[4];
        #pragma unroll
        for (int q = 0; q < 4; ++q) r2[q] = (f32x2){bv, bv};
        #pragma unroll
        for (int j = 0; j < 10; ++j) {
            const float w = wr[j];
            const f32x2 W = {w, w};
            #pragma unroll
            for (int q = 0; q < 4; ++q)
                r2[q] = __builtin_elementwise_fma(acc2[j][q], W, r2[q]);
        }
        float* op = ob + (size_t)dd * LP;
        if (full) {
            #pragma unroll
            for (int q = 0; q < 4; ++q)
                *reinterpret_cast<float2*>(op + 2 * q) =
                    make_float2(r2[q][0], r2[q][1]);
        } else {
            #pragma unroll
            for (int q = 0; q < 4; ++q) {
                if (l + 2 * q     < LP) op[2 * q]     = r2[q][0];
                if (l + 2 * q + 1 < LP) op[2 * q + 1] = r2[q][1];
            }
        }
    }
}

extern "C" void kernel_launch(void* const* d_in, const int* in_sizes, int n_in,
                              void* d_out, int out_size, void* d_ws, size_t ws_size,
                              hipStream_t stream) {
    (void)in_sizes; (void)n_in; (void)out_size; (void)ws_size;
    const float* x  = (const float*)d_in[0];
    const float* w1 = (const float*)d_in[1];
    const float* b1 = (const float*)d_in[2];
    const float* w2 = (const float*)d_in[3];
    const float* b2 = (const float*)d_in[4];
    const float* wg = (const float*)d_in[5];
    float* out      = (float*)d_out;
    float* gws      = (float*)d_ws;                         // [B,G,E]
    float* w1t      = (float*)d_ws + B_ * G_ * E_;          // [g][d][32]
    float* loss_out = out + COMBINE_SIZE;
    float* gout     = out + COMBINE_SIZE + 1;

    repack_kernel<<<(G_ * 32 * 30 + 255) / 256, 256, 0, stream>>>(w1, w1t);
    conv_kernel<<<B_ * G_, 512, 0, stream>>>(x, w1t, b1, w2, b2, wg,
                                             out, gws, gout);
    loss_kernel<<<1, 64, 0, stream>>>(gws, loss_out);
}